// Round 1
// baseline (779.522 us; speedup 1.0000x reference)
//
#include <hip/hip_runtime.h>
#include <stdint.h>

// Problem constants
#define S_LEN 512
#define NBATCH 128
#define NT 9          // tags

typedef __attribute__((ext_vector_type(8)))  short          bf16x8;
typedef __attribute__((ext_vector_type(4)))  float          f32x4;
typedef __attribute__((ext_vector_type(16))) unsigned short u16x16;
typedef __attribute__((ext_vector_type(4)))  unsigned int   u32x4;

static __device__ __forceinline__ unsigned short f2bf(float f) {
    union { float f; unsigned u; } c; c.f = f;
    return (unsigned short)((c.u + 0x7fffu + ((c.u >> 16) & 1u)) >> 16); // RNE
}
static __device__ __forceinline__ float bf2f(unsigned short h) {
    union { unsigned u; float f; } c; c.u = ((unsigned)h) << 16;
    return c.f;
}
static __device__ __forceinline__ bf16x8 cvt8(const float* p) {
    f32x4 a = *(const f32x4*)p, b = *(const f32x4*)(p + 4);
    bf16x8 fr;
    fr[0]=(short)f2bf(a[0]); fr[1]=(short)f2bf(a[1]); fr[2]=(short)f2bf(a[2]); fr[3]=(short)f2bf(a[3]);
    fr[4]=(short)f2bf(b[0]); fr[5]=(short)f2bf(b[1]); fr[6]=(short)f2bf(b[2]); fr[7]=(short)f2bf(b[3]);
    return fr;
}
static __device__ __forceinline__ float sigf(float x) {
    return __builtin_amdgcn_rcpf(1.0f + __expf(-x));
}
static __device__ __forceinline__ float tanhf_(float x) {
    return 1.0f - 2.0f * __builtin_amdgcn_rcpf(1.0f + __expf(2.0f * x));
}

// ---------------------------------------------------------------------------
// Kernel 1: xg[dir][b][s][gate] = emb[x[b][s]] @ W_ih[dir]^T + b[dir]
// Stored bf16 in MFMA C-fragment order so k_lstm reads 32B/lane contiguous.
// Layout: xg[ (((s*2+dir)*8 + btile)*8192 ) + tid*16 + (q*4 + j) ]
//   where tid = wave*64+lane; gate = q*128 + wave*16 + (lane&15);
//   row (batch within tile) = (lane>>4)*4 + j.
// ---------------------------------------------------------------------------
__global__ __launch_bounds__(512) void k_xg(
    const int* __restrict__ x, const float* __restrict__ embed,
    const float* __restrict__ Wf, const float* __restrict__ bF,
    const float* __restrict__ Wb, const float* __restrict__ bB,
    unsigned short* __restrict__ xg)
{
    const int dir = blockIdx.y;
    const float* __restrict__ W    = dir ? Wb : Wf;
    const float* __restrict__ bias = dir ? bB : bF;
    const int tid = threadIdx.x;
    const int w = tid >> 6, L = tid & 63, l15 = L & 15, l4 = L >> 4;

    // W_ih B-fragments live in registers for the whole kernel (64 VGPR)
    bf16x8 Bf[4][4];
    float  bq[4];
#pragma unroll
    for (int q = 0; q < 4; ++q) {
        const int gate = q * 128 + w * 16 + l15;
        bq[q] = bias[gate];
#pragma unroll
        for (int kt = 0; kt < 4; ++kt)
            Bf[q][kt] = cvt8(W + gate * 128 + kt * 32 + l4 * 8);
    }

    __shared__ int tok[16];

    for (int mt = 0; mt < 32; ++mt) {
        const int s  = blockIdx.x * 4 + (mt >> 3);
        const int bt = mt & 7;
        __syncthreads();
        if (tid < 16) tok[tid] = x[(bt * 16 + tid) * S_LEN + s];
        __syncthreads();
        // A-fragments: direct gather from embed (rows L1/L2-resident across waves)
        const float* erow = embed + (size_t)tok[l15] * 128;
        bf16x8 A[4];
#pragma unroll
        for (int kt = 0; kt < 4; ++kt)
            A[kt] = cvt8(erow + kt * 32 + l4 * 8);

        unsigned short ov[16];
#pragma unroll
        for (int q = 0; q < 4; ++q) {
            f32x4 acc = { bq[q], bq[q], bq[q], bq[q] };
#pragma unroll
            for (int kt = 0; kt < 4; ++kt)
                acc = __builtin_amdgcn_mfma_f32_16x16x32_bf16(A[kt], Bf[q][kt], acc, 0, 0, 0);
            ov[q*4+0] = f2bf(acc[0]); ov[q*4+1] = f2bf(acc[1]);
            ov[q*4+2] = f2bf(acc[2]); ov[q*4+3] = f2bf(acc[3]);
        }
        unsigned short* dst = xg + ((((size_t)s * 2 + dir) * 8 + bt) * 8192 + (size_t)tid * 16);
        *(u32x4*)dst       = *(const u32x4*)&ov[0];
        *(u32x4*)(dst + 8) = *(const u32x4*)&ov[8];
    }
}

// ---------------------------------------------------------------------------
// Kernel 2: sequential LSTM over S per (direction, batch-tile of 16).
// W_hh in registers as B-frags; h tile in LDS (XOR-swizzled bf16 [16][128]).
// Wave 0 additionally computes the emission partial (h . W_out-half) via MFMA.
// ---------------------------------------------------------------------------
__global__ __launch_bounds__(512) void k_lstm(
    const unsigned short* __restrict__ xg,
    const float* __restrict__ Whf, const float* __restrict__ Whb,
    const float* __restrict__ Wout, float* __restrict__ emp)
{
    const int dir = blockIdx.y, bt = blockIdx.x;
    const float* __restrict__ Wh = dir ? Whb : Whf;
    const int tid = threadIdx.x, w = tid >> 6, L = tid & 63, l15 = L & 15, l4 = L >> 4;

    bf16x8 Bf[4][4];
#pragma unroll
    for (int q = 0; q < 4; ++q)
#pragma unroll
        for (int kt = 0; kt < 4; ++kt)
            Bf[q][kt] = cvt8(Wh + (q * 128 + w * 16 + l15) * 128 + kt * 32 + l4 * 8);

    bf16x8 Of[4];                    // W_out fragments (wave 0 only), cols >= NT are zero
#pragma unroll
    for (int kt = 0; kt < 4; ++kt) { bf16x8 z; 
#pragma unroll
        for (int i = 0; i < 8; ++i) z[i] = 0; Of[kt] = z; }
    if (w == 0 && l15 < NT) {
#pragma unroll
        for (int kt = 0; kt < 4; ++kt)
            Of[kt] = cvt8(Wout + l15 * 256 + dir * 128 + kt * 32 + l4 * 8);
    }

    __shared__ unsigned short hlds[2048];    // 16 rows x 128 cols bf16, XOR-swizzled
    for (int i = tid; i < 2048; i += 512) hlds[i] = 0;

    f32x4 cst = {0.f, 0.f, 0.f, 0.f};        // c-state, f32 per (row j)

    u16x16 xcur = *(const u16x16*)(xg + ((((size_t)(dir ? 511 : 0) * 2 + dir) * 8 + bt) * 8192 + (size_t)tid * 16));

    __syncthreads();

    for (int t = 0; t < 512; ++t) {
        // prefetch next step's xg fragment
        u16x16 xnxt = xcur;
        if (t < 511) {
            const int s2 = dir ? (510 - t) : (t + 1);
            xnxt = *(const u16x16*)(xg + ((((size_t)s2 * 2 + dir) * 8 + bt) * 8192 + (size_t)tid * 16));
        }
        // A-frags: h_{t-1} from swizzled LDS (2-way conflicts only)
        bf16x8 A[4];
#pragma unroll
        for (int kt = 0; kt < 4; ++kt) {
            int byte = l15 * 256 + kt * 64 + l4 * 16;
            byte ^= (l15 & 7) << 4;
            A[kt] = *(const bf16x8*)((const char*)hlds + byte);
        }
        // gates = xg + h @ W_hh^T
        f32x4 acc[4];
#pragma unroll
        for (int q = 0; q < 4; ++q) {
            f32x4 a0 = { bf2f(xcur[q*4+0]), bf2f(xcur[q*4+1]), bf2f(xcur[q*4+2]), bf2f(xcur[q*4+3]) };
#pragma unroll
            for (int kt = 0; kt < 4; ++kt)
                a0 = __builtin_amdgcn_mfma_f32_16x16x32_bf16(A[kt], Bf[q][kt], a0, 0, 0, 0);
            acc[q] = a0;
        }
        // emission partial for the PREVIOUS position (A holds h of step t-1)
        if (w == 0 && t > 0) {
            const int sp = dir ? (512 - t) : (t - 1);
            f32x4 em0 = {0, 0, 0, 0};
#pragma unroll
            for (int kt = 0; kt < 4; ++kt)
                em0 = __builtin_amdgcn_mfma_f32_16x16x32_bf16(A[kt], Of[kt], em0, 0, 0, 0);
            if (l15 < NT) {
#pragma unroll
                for (int j = 0; j < 4; ++j)
                    emp[(((size_t)(dir * 128 + bt * 16 + l4 * 4 + j)) * 512 + sp) * 9 + l15] = em0[j];
            }
        }
        // pointwise: i,f,g,o (JAX split order), f32 c-state
        float hv[4];
#pragma unroll
        for (int j = 0; j < 4; ++j) {
            float ig = sigf(acc[0][j]);
            float fg = sigf(acc[1][j]);
            float gg = tanhf_(acc[2][j]);
            float og = sigf(acc[3][j]);
            float cn = fg * cst[j] + ig * gg;
            cst[j] = cn;
            hv[j] = og * tanhf_(cn);
        }
        __syncthreads();                         // WAR: all waves done reading hlds
#pragma unroll
        for (int j = 0; j < 4; ++j) {
            const int r = l4 * 4 + j, hc = w * 16 + l15;
            int byte = r * 256 + hc * 2;
            byte ^= (r & 7) << 4;
            *(unsigned short*)((char*)hlds + byte) = f2bf(hv[j]);
        }
        xcur = xnxt;
        __syncthreads();                         // RAW for next step
    }
    // final position's emission
    if (w == 0) {
        bf16x8 A[4];
#pragma unroll
        for (int kt = 0; kt < 4; ++kt) {
            int byte = l15 * 256 + kt * 64 + l4 * 16;
            byte ^= (l15 & 7) << 4;
            A[kt] = *(const bf16x8*)((const char*)hlds + byte);
        }
        const int sp = dir ? 0 : 511;
        f32x4 em0 = {0, 0, 0, 0};
#pragma unroll
        for (int kt = 0; kt < 4; ++kt)
            em0 = __builtin_amdgcn_mfma_f32_16x16x32_bf16(A[kt], Of[kt], em0, 0, 0, 0);
        if (l15 < NT) {
#pragma unroll
            for (int j = 0; j < 4; ++j)
                emp[(((size_t)(dir * 128 + bt * 16 + l4 * 4 + j)) * 512 + sp) * 9 + l15] = em0[j];
        }
    }
}

// ---------------------------------------------------------------------------
// Kernel 3: Viterbi per batch row (1 wave). Forward DP with shuffles,
// LDS backpointers, lane-0 backtrace. First-index argmax tie-breaking.
// ---------------------------------------------------------------------------
__global__ __launch_bounds__(64) void k_viterbi(
    const float* __restrict__ emp, const int* __restrict__ mask,
    const float* __restrict__ bout, const float* __restrict__ startt,
    const float* __restrict__ trans, const float* __restrict__ endt,
    float* __restrict__ out)
{
    const int b = blockIdx.x, tid = threadIdx.x;
    __shared__ float em[512 * 9];
    __shared__ float tr[81];
    __shared__ int   msk[512];
    __shared__ unsigned char hist[512 * 9];

    const float* pf = emp + (size_t)b * 4608;
    const float* pb = emp + (size_t)(128 + b) * 4608;
    for (int i = tid; i < 4608; i += 64) em[i] = pf[i] + pb[i] + bout[i % 9];
    for (int i = tid; i < 512; i += 64) msk[i] = mask[b * 512 + i];
    if (tid < 81) tr[tid] = trans[tid];
    __syncthreads();

    const int k = (tid < NT) ? tid : 0;
    float score = (tid < NT) ? (startt[tid] + em[tid]) : -3e38f;

    for (int t = 1; t < 512; ++t) {
        float m = -3e38f; int bi = 0;
#pragma unroll
        for (int j = 0; j < NT; ++j) {
            float v = __shfl(score, j, 64) + tr[j * 9 + k];
            if (v > m) { m = v; bi = j; }     // strict > keeps first (np.argmax)
        }
        if (msk[t]) score = m + em[t * 9 + k];
        if (tid < NT) hist[t * 9 + tid] = (unsigned char)bi;
    }
    float fin = (tid < NT) ? (score + endt[tid]) : -3e38f;
    float bs = -3e38f; int cur = 0;
#pragma unroll
    for (int j = 0; j < NT; ++j) {
        float v = __shfl(fin, j, 64);
        if (v > bs) { bs = v; cur = j; }
    }
    if (tid == 0) {
        out[65536 + b] = bs;
        int c = cur;
        for (int t = 511; t >= 1; --t) {
            const int mt = msk[t];
            out[b * 512 + t] = (float)(mt ? c : -1);
            if (mt) c = (int)hist[t * 9 + c];
        }
        out[b * 512] = (float)c;
    }
}

// ---------------------------------------------------------------------------
extern "C" void kernel_launch(void* const* d_in, const int* in_sizes, int n_in,
                              void* d_out, int out_size, void* d_ws, size_t ws_size,
                              hipStream_t stream) {
    const int*   x      = (const int*)d_in[0];
    const int*   mask   = (const int*)d_in[1];
    const float* embed  = (const float*)d_in[2];
    const float* Wihf   = (const float*)d_in[3];
    const float* Whhf   = (const float*)d_in[4];
    const float* bf_    = (const float*)d_in[5];
    const float* Wihb   = (const float*)d_in[6];
    const float* Whhb   = (const float*)d_in[7];
    const float* bb_    = (const float*)d_in[8];
    const float* Wout   = (const float*)d_in[9];
    const float* bout   = (const float*)d_in[10];
    const float* startt = (const float*)d_in[11];
    const float* trans  = (const float*)d_in[12];
    const float* endt   = (const float*)d_in[13];

    unsigned short* xg  = (unsigned short*)d_ws;                       // 128 MB bf16
    float*          emp = (float*)((char*)d_ws + (size_t)134217728);   // 4.5 MB f32
    float*          out = (float*)d_out;

    k_xg     <<<dim3(128, 2), 512, 0, stream>>>(x, embed, Wihf, bf_, Wihb, bb_, xg);
    k_lstm   <<<dim3(8, 2),   512, 0, stream>>>(xg, Whhf, Whhb, Wout, emp);
    k_viterbi<<<128,          64,  0, stream>>>(emp, mask, bout, startt, trans, endt, out);
}

// Round 2
// 485.885 us; speedup vs baseline: 1.6043x; 1.6043x over previous
//
#include <hip/hip_runtime.h>
#include <stdint.h>

#define S_LEN 512
#define NT 9

typedef __attribute__((ext_vector_type(8)))  short          bf16x8;
typedef __attribute__((ext_vector_type(4)))  float          f32x4;
typedef __attribute__((ext_vector_type(16))) unsigned short u16x16;
typedef __attribute__((ext_vector_type(4)))  unsigned int   u32x4;

static __device__ __forceinline__ unsigned short f2bf(float f) {
    union { float f; unsigned u; } c; c.f = f;
    return (unsigned short)((c.u + 0x7fffu + ((c.u >> 16) & 1u)) >> 16); // RNE
}
static __device__ __forceinline__ float bf2f(unsigned short h) {
    union { unsigned u; float f; } c; c.u = ((unsigned)h) << 16;
    return c.f;
}
static __device__ __forceinline__ bf16x8 cvt8(const float* p) {
    f32x4 a = *(const f32x4*)p, b = *(const f32x4*)(p + 4);
    bf16x8 fr;
    fr[0]=(short)f2bf(a[0]); fr[1]=(short)f2bf(a[1]); fr[2]=(short)f2bf(a[2]); fr[3]=(short)f2bf(a[3]);
    fr[4]=(short)f2bf(b[0]); fr[5]=(short)f2bf(b[1]); fr[6]=(short)f2bf(b[2]); fr[7]=(short)f2bf(b[3]);
    return fr;
}
static __device__ __forceinline__ float sigf(float x) {
    return __builtin_amdgcn_rcpf(1.0f + __expf(-x));
}
static __device__ __forceinline__ float tanhf_(float x) {
    return 1.0f - 2.0f * __builtin_amdgcn_rcpf(1.0f + __expf(2.0f * x));
}
static __device__ __forceinline__ float sel4(f32x4 a, int l4) {
    float x01 = (l4 & 1) ? a[1] : a[0];
    float x23 = (l4 & 1) ? a[3] : a[2];
    return (l4 & 2) ? x23 : x01;
}

// ---------------------------------------------------------------------------
// Kernel 1: xg = emb[x] @ W_ih^T + b, stored bf16 in the k_lstm-friendly order:
//   xg[s][dir][bt(32 tiles of 4 rows)][w(8)][l15(16)][q(4)][j(4)]
// Each lane stores/loads 32B contiguous. Embed rows staged in LDS (bf16,
// XOR-swizzled) via coalesced loads; next tile's stage prefetched to regs.
// ---------------------------------------------------------------------------
__global__ __launch_bounds__(512) void k_xg(
    const int* __restrict__ x, const float* __restrict__ embed,
    const float* __restrict__ Wf, const float* __restrict__ bF,
    const float* __restrict__ Wb, const float* __restrict__ bB,
    unsigned short* __restrict__ xg)
{
    const int dir = blockIdx.y;
    const float* __restrict__ W    = dir ? Wb : Wf;
    const float* __restrict__ bias = dir ? bB : bF;
    const int tid = threadIdx.x;
    const int wv = tid >> 6, L = tid & 63, l15 = L & 15, l4 = L >> 4;
    const int s0 = blockIdx.x * 4;

    // W_ih B-fragments in registers (64 VGPR)
    bf16x8 Bf[4][4];
    float  bq[4];
#pragma unroll
    for (int q = 0; q < 4; ++q) {
        const int gate = q * 128 + wv * 16 + l15;
        bq[q] = bias[gate];
#pragma unroll
        for (int kt = 0; kt < 4; ++kt)
            Bf[q][kt] = cvt8(W + gate * 128 + kt * 32 + l4 * 8);
    }

    __shared__ int tokL[512];                 // tokens for 4 s x 128 rows
    __shared__ unsigned short stage[2048];    // 16 rows x 128 bf16, swizzled

    tokL[tid] = x[(tid >> 2) * S_LEN + s0 + (tid & 3)];
    const int srow = tid >> 5, scol = tid & 31;
    __syncthreads();

    // prefetch tile 0
    f32x4 vnext = *(const f32x4*)(embed + (size_t)tokL[srow] * 128 + scol * 4);

    for (int mt = 0; mt < 32; ++mt) {
        const int si = mt >> 3, bt16 = mt & 7;
        __syncthreads();   // WAR: previous tile's A-reads done
        {
            unsigned short b4[4];
            b4[0]=f2bf(vnext[0]); b4[1]=f2bf(vnext[1]); b4[2]=f2bf(vnext[2]); b4[3]=f2bf(vnext[3]);
            int byte = srow * 256 + ((scol * 8) ^ ((srow & 7) << 4));
            *(uint2*)((char*)stage + byte) = *(const uint2*)b4;
        }
        __syncthreads();   // stage ready
        if (mt < 31) {
            const int si2 = (mt + 1) >> 3, bt2 = (mt + 1) & 7;
            vnext = *(const f32x4*)(embed + (size_t)tokL[si2 * 128 + bt2 * 16 + srow] * 128 + scol * 4);
        }
        bf16x8 A[4];
#pragma unroll
        for (int kt = 0; kt < 4; ++kt) {
            int byte = l15 * 256 + ((kt * 64 + l4 * 16) ^ ((l15 & 7) << 4));
            A[kt] = *(const bf16x8*)((const char*)stage + byte);
        }
        unsigned short ov[16];
#pragma unroll
        for (int q = 0; q < 4; ++q) {
            f32x4 acc = { bq[q], bq[q], bq[q], bq[q] };
#pragma unroll
            for (int kt = 0; kt < 4; ++kt)
                acc = __builtin_amdgcn_mfma_f32_16x16x32_bf16(A[kt], Bf[q][kt], acc, 0, 0, 0);
            ov[q*4+0]=f2bf(acc[0]); ov[q*4+1]=f2bf(acc[1]);
            ov[q*4+2]=f2bf(acc[2]); ov[q*4+3]=f2bf(acc[3]);
        }
        const int s = s0 + si;
        unsigned short* dst = xg +
            (((((size_t)s * 2 + dir) * 32 + bt16 * 4 + l4) * 8 + wv) * 256 + l15 * 16);
        *(u32x4*)dst       = *(const u32x4*)&ov[0];
        *(u32x4*)(dst + 8) = *(const u32x4*)&ov[8];
    }
}

// ---------------------------------------------------------------------------
// Kernel 2: LSTM recurrence, 64 WGs x 4 batch rows. A-rows & C-init duplicated
// (row l15&3) so every lane's acc[q][j] = gates for batch row j; select j=l4.
// h double-buffered in LDS with granule rotation. Emission MFMA multiplexed
// over waves by t&7.
// ---------------------------------------------------------------------------
__global__ __launch_bounds__(512) void k_lstm(
    const unsigned short* __restrict__ xg,
    const float* __restrict__ Whf, const float* __restrict__ Whb,
    const float* __restrict__ Wout, float* __restrict__ emp)
{
    const int dir = blockIdx.y, bt = blockIdx.x;       // bt: 0..31 (4-row tiles)
    const float* __restrict__ Wh = dir ? Whb : Whf;
    const int tid = threadIdx.x, w = tid >> 6, L = tid & 63, l15 = L & 15, l4 = L >> 4;

    bf16x8 Bf[4][4];
#pragma unroll
    for (int q = 0; q < 4; ++q)
#pragma unroll
        for (int kt = 0; kt < 4; ++kt)
            Bf[q][kt] = cvt8(Wh + (q * 128 + w * 16 + l15) * 128 + kt * 32 + l4 * 8);

    bf16x8 Of[4];
#pragma unroll
    for (int kt = 0; kt < 4; ++kt) { bf16x8 z;
#pragma unroll
        for (int i = 0; i < 8; ++i) z[i] = 0; Of[kt] = z; }
    if (l15 < NT) {
#pragma unroll
        for (int kt = 0; kt < 4; ++kt)
            Of[kt] = cvt8(Wout + l15 * 256 + dir * 128 + kt * 32 + l4 * 8);
    }

    __shared__ unsigned short hl[2048];   // 2 bufs x 4 rows x 256B, rotated granules
    for (int i = tid; i < 1024; i += 512) ((unsigned*)hl)[i] = 0;

    // A-read byte offsets (row = l15&3, granule rotation (g + 2*row)&15)
    const int ar = l15 & 3;
    int rdoff[4];
#pragma unroll
    for (int kt = 0; kt < 4; ++kt) {
        int p = (kt * 4 + l4 + 2 * ar) & 15;
        rdoff[kt] = ar * 256 + p * 16;
    }
    // h write offset: row=l4, col hc
    const int hc = w * 16 + l15;
    const int wroff = l4 * 256 + (((hc >> 3) + 2 * l4) & 15) * 16 + (hc & 7) * 2;

    float c = 0.f;
    const size_t xstep = (size_t)2 * 32 * 8 * 256;   // elements per s
    const size_t xbase = (((size_t)dir * 32 + bt) * 8 + w) * 256 + l15 * 16;

    u16x16 xcur = *(const u16x16*)(xg + xbase + (size_t)(dir ? 511 : 0) * xstep);
    __syncthreads();

    for (int t = 0; t < 512; ++t) {
        const char* bufR = (const char*)hl + (t & 1) * 1024;
        char*       bufW = (char*)hl + ((t & 1) ^ 1) * 1024;

        u16x16 xnxt = xcur;
        if (t < 511) {
            const int s2 = dir ? (510 - t) : (t + 1);
            xnxt = *(const u16x16*)(xg + xbase + (size_t)s2 * xstep);
        }
        bf16x8 A[4];
#pragma unroll
        for (int kt = 0; kt < 4; ++kt)
            A[kt] = *(const bf16x8*)(bufR + rdoff[kt]);

        f32x4 acc[4];
#pragma unroll
        for (int q = 0; q < 4; ++q) {
            f32x4 a0 = { bf2f(xcur[q*4+0]), bf2f(xcur[q*4+1]), bf2f(xcur[q*4+2]), bf2f(xcur[q*4+3]) };
#pragma unroll
            for (int kt = 0; kt < 4; ++kt)
                a0 = __builtin_amdgcn_mfma_f32_16x16x32_bf16(A[kt], Bf[q][kt], a0, 0, 0, 0);
            acc[q] = a0;
        }
        // emission for position of h_{t-1}; wave (t&7) does it (A is wave-invariant)
        if (t > 0 && w == (t & 7)) {
            f32x4 em0 = {0, 0, 0, 0};
#pragma unroll
            for (int kt = 0; kt < 4; ++kt)
                em0 = __builtin_amdgcn_mfma_f32_16x16x32_bf16(A[kt], Of[kt], em0, 0, 0, 0);
            if (l4 == 0 && l15 < NT) {
                const int sp = dir ? (512 - t) : (t - 1);
#pragma unroll
                for (int j = 0; j < 4; ++j)
                    emp[((size_t)(dir * 128 + bt * 4 + j) * 512 + sp) * 9 + l15] = em0[j];
            }
        }
        // pointwise: one (row=l4, hc) pair per lane
        float ig = sigf(sel4(acc[0], l4));
        float fg = sigf(sel4(acc[1], l4));
        float gg = tanhf_(sel4(acc[2], l4));
        float og = sigf(sel4(acc[3], l4));
        c = fg * c + ig * gg;
        float h = og * tanhf_(c);
        *(unsigned short*)(bufW + wroff) = f2bf(h);
        xcur = xnxt;
        __syncthreads();
    }
    // final position emission (h from t=511 sits in buf 0)
    if (w == 0) {
        bf16x8 A[4];
#pragma unroll
        for (int kt = 0; kt < 4; ++kt)
            A[kt] = *(const bf16x8*)((const char*)hl + rdoff[kt]);
        f32x4 em0 = {0, 0, 0, 0};
#pragma unroll
        for (int kt = 0; kt < 4; ++kt)
            em0 = __builtin_amdgcn_mfma_f32_16x16x32_bf16(A[kt], Of[kt], em0, 0, 0, 0);
        if (l4 == 0 && l15 < NT) {
            const int sp = dir ? 0 : 511;
#pragma unroll
            for (int j = 0; j < 4; ++j)
                emp[((size_t)(dir * 128 + bt * 4 + j) * 512 + sp) * 9 + l15] = em0[j];
        }
    }
}

// ---------------------------------------------------------------------------
// Kernel 3: Viterbi. 256-thread staging; wave-0 forward DP with hoisted
// transitions; blocked backtrace (32 composition maps of 16 steps).
// ---------------------------------------------------------------------------
__global__ __launch_bounds__(256) void k_viterbi(
    const float* __restrict__ emp, const int* __restrict__ mask,
    const float* __restrict__ bout, const float* __restrict__ startt,
    const float* __restrict__ trans, const float* __restrict__ endt,
    float* __restrict__ out)
{
    const int b = blockIdx.x, tid = threadIdx.x;
    __shared__ float em[512 * 9];
    __shared__ int   msk[512];
    __shared__ unsigned char hist[512 * 9];
    __shared__ unsigned char Gl[32 * 12];
    __shared__ unsigned char bound[32];
    __shared__ int curS;

    const float* pf = emp + (size_t)b * 4608;
    const float* pb = emp + (size_t)(128 + b) * 4608;
    for (int i = tid; i < 4608; i += 256) {
        unsigned q = ((unsigned)i * 7282u) >> 16;          // i/9 for i<4608
        em[i] = pf[i] + pb[i] + bout[i - 9 * q];
    }
    for (int i = tid; i < 512; i += 256) msk[i] = mask[b * 512 + i];
    __syncthreads();

    if (tid < 64) {   // wave 0: forward DP
        const int k = (tid < NT) ? tid : 0;
        float trk[9];
#pragma unroll
        for (int j = 0; j < NT; ++j) trk[j] = trans[j * 9 + k];
        float score = startt[k] + em[k];
        for (int t = 1; t < 512; ++t) {
            float v[9];
#pragma unroll
            for (int j = 0; j < NT; ++j) v[j] = __shfl(score, j, 64) + trk[j];
            float m01 = fmaxf(v[0], v[1]), m23 = fmaxf(v[2], v[3]);
            float m45 = fmaxf(v[4], v[5]), m67 = fmaxf(v[6], v[7]);
            float m = fmaxf(fmaxf(fmaxf(m01, m23), fmaxf(m45, m67)), v[8]);
            int bi = 0;
#pragma unroll
            for (int j = 8; j >= 0; --j) if (v[j] == m) bi = j;   // first index
            if (msk[t]) score = m + em[t * 9 + k];
            if (tid < NT) hist[t * 9 + tid] = (unsigned char)bi;
        }
        float fin = score + endt[k];
        float bs = -3e38f; int cur = 0;
#pragma unroll
        for (int j = 0; j < NT; ++j) {
            float vv = __shfl(fin, j, 64);
            if (vv > bs) { bs = vv; cur = j; }
        }
        if (tid == 0) { curS = cur; out[65536 + b] = bs; }
    }
    __syncthreads();

    // block composition maps: block m covers t in [16m+1, min(16m+16,511)]
    if (tid < 32) {
        const int m = tid;
        int G[9];
#pragma unroll
        for (int k = 0; k < NT; ++k) G[k] = k;
        const int hi = (m == 31) ? 511 : (16 * m + 16);
        for (int t = hi; t >= 16 * m + 1; --t) {
            if (msk[t]) {
#pragma unroll
                for (int k = 0; k < NT; ++k) G[k] = hist[t * 9 + G[k]];
            }
        }
#pragma unroll
        for (int k = 0; k < NT; ++k) Gl[m * 12 + k] = (unsigned char)G[k];
    }
    __syncthreads();

    if (tid == 0) {   // serial boundary walk (31 steps)
        int e = curS;
        bound[31] = (unsigned char)e;
        for (int m = 31; m >= 1; --m) { e = Gl[m * 12 + e]; bound[m - 1] = (unsigned char)e; }
        out[(size_t)b * 512] = (float)Gl[0 * 12 + e];   // c_0
    }
    __syncthreads();

    if (tid < 32) {   // lane-parallel interior backtrace
        const int m = tid;
        int ccur = bound[m];
        const int hi = (m == 31) ? 511 : (16 * m + 16);
        for (int t = hi; t >= 16 * m + 1; --t) {
            const int mt = msk[t];
            out[(size_t)b * 512 + t] = (float)(mt ? ccur : -1);
            if (mt) ccur = hist[t * 9 + ccur];
        }
    }
}

// ---------------------------------------------------------------------------
extern "C" void kernel_launch(void* const* d_in, const int* in_sizes, int n_in,
                              void* d_out, int out_size, void* d_ws, size_t ws_size,
                              hipStream_t stream) {
    const int*   x      = (const int*)d_in[0];
    const int*   mask   = (const int*)d_in[1];
    const float* embed  = (const float*)d_in[2];
    const float* Wihf   = (const float*)d_in[3];
    const float* Whhf   = (const float*)d_in[4];
    const float* bf_    = (const float*)d_in[5];
    const float* Wihb   = (const float*)d_in[6];
    const float* Whhb   = (const float*)d_in[7];
    const float* bb_    = (const float*)d_in[8];
    const float* Wout   = (const float*)d_in[9];
    const float* bout   = (const float*)d_in[10];
    const float* startt = (const float*)d_in[11];
    const float* trans  = (const float*)d_in[12];
    const float* endt   = (const float*)d_in[13];

    unsigned short* xg  = (unsigned short*)d_ws;                       // 128 MB bf16
    float*          emp = (float*)((char*)d_ws + (size_t)134217728);   // 4.5 MB f32
    float*          out = (float*)d_out;

    k_xg     <<<dim3(128, 2), 512, 0, stream>>>(x, embed, Wihf, bf_, Wihb, bb_, xg);
    k_lstm   <<<dim3(32, 2),  512, 0, stream>>>(xg, Whhf, Whhb, Wout, emp);
    k_viterbi<<<128,          256, 0, stream>>>(emp, mask, bout, startt, trans, endt, out);
}